// Round 6
// baseline (1283.511 us; speedup 1.0000x reference)
//
#include <hip/hip_runtime.h>
#include <hip/hip_bf16.h>

#define FIN 128
#define HID 64
#define BSN 128            // dst nodes per bucket
#define BSHIFT 7
#define SRCBITS 20         // src fits in 20 bits (N < 1M)
#define EPB 8192           // edges per binning block
#define CHUNK 16384        // src nodes per L2 chunk (2 MB of bf16 rows)
#define CSHIFT 14
#define MAXSB 6144         // >= C*B = 7*782 = 5474 for N=100000
#define KN 25              // nodes per wave in pull
#define NPB 200            // nodes per 512-thr block (8 waves * 25)

typedef __attribute__((ext_vector_type(8))) short short8;
typedef __attribute__((ext_vector_type(4))) float floatx4;

__device__ __forceinline__ float bf2f(unsigned short u) {
    union { unsigned int i; float f; } c;
    c.i = ((unsigned int)u) << 16;
    return c.f;
}

__device__ __forceinline__ unsigned short f2bf(float f) {
    union { float f; unsigned int i; } c;
    c.f = f;
    unsigned int u = c.i;
    unsigned int r = (u + 0x7FFFu + ((u >> 16) & 1u)) >> 16;   // RNE
    return (unsigned short)r;
}

// best-effort grid barrier: pure performance hint (phase L2 locality).
// Correctness never depends on it — gathered data is read-only in-kernel.
__device__ __forceinline__ void softbar(int* ctr, int nblk) {
    __syncthreads();
    if (threadIdx.x == 0) {
        __threadfence();
        atomicAdd(ctr, 1);
        for (int spin = 0; spin < 30000; ++spin) {
            if (__hip_atomic_load(ctr, __ATOMIC_RELAXED, __HIP_MEMORY_SCOPE_AGENT) >= nblk)
                break;
            __builtin_amdgcn_s_sleep(2);
        }
    }
    __syncthreads();
}

// ---------------- super-bucket histogram: key = (src>>CSHIFT)*B + (dst>>BSHIFT)
__global__ void bin_count(const int* __restrict__ src, const int* __restrict__ dst,
                          int* __restrict__ bcnt, int E, int B) {
    __shared__ int hist[MAXSB];
    for (int i = threadIdx.x; i < MAXSB; i += 256) hist[i] = 0;
    __syncthreads();
    int base = blockIdx.x * EPB;
    int lim = min(base + EPB, E);
    for (int e = base + threadIdx.x; e < lim; e += 256)
        atomicAdd(&hist[(src[e] >> CSHIFT) * B + (dst[e] >> BSHIFT)], 1);
    __syncthreads();
    for (int b = threadIdx.x; b < MAXSB; b += 256)
        if (hist[b]) atomicAdd(&bcnt[b], hist[b]);
}

// ---------------- scan super-bucket counts; bcnt becomes chunk cursor -------
__global__ void scan_bkt(int* __restrict__ bcnt, int* __restrict__ bbase,
                         int E, int SB) {
    __shared__ int s[1024];
    int t = threadIdx.x;
    int base = t * 6;
    int loc[6];
    int sum = 0;
#pragma unroll
    for (int i = 0; i < 6; ++i) {
        int idx = base + i;
        int v = (idx < SB) ? bcnt[idx] : 0;
        loc[i] = sum;
        sum += v;
    }
    s[t] = sum;
    __syncthreads();
    for (int off = 1; off < 1024; off <<= 1) {
        int a = (t >= off) ? s[t - off] : 0;
        __syncthreads();
        s[t] += a;
        __syncthreads();
    }
    int tex = s[t] - sum;
#pragma unroll
    for (int i = 0; i < 6; ++i) {
        int idx = base + i;
        if (idx < SB) { int ex = tex + loc[i]; bbase[idx] = ex; bcnt[idx] = ex; }
    }
    if (t == 0) bbase[SB] = E;
}

// ---------------- scatter packed records into per-super-bucket chunks -------
__global__ void bin_fill(const int* __restrict__ src, const int* __restrict__ dst,
                         int* __restrict__ bcur, unsigned* __restrict__ rec,
                         int E, int B) {
    __shared__ int hist[MAXSB];
    __shared__ int cbase[MAXSB];
    for (int i = threadIdx.x; i < MAXSB; i += 256) hist[i] = 0;
    __syncthreads();
    int base = blockIdx.x * EPB;
    int lim = min(base + EPB, E);
    for (int e = base + threadIdx.x; e < lim; e += 256)
        atomicAdd(&hist[(src[e] >> CSHIFT) * B + (dst[e] >> BSHIFT)], 1);
    __syncthreads();
    for (int b = threadIdx.x; b < MAXSB; b += 256) {
        int c = hist[b];
        cbase[b] = c ? atomicAdd(&bcur[b], c) : 0;
    }
    __syncthreads();
    for (int i = threadIdx.x; i < MAXSB; i += 256) hist[i] = 0;
    __syncthreads();
    for (int e = base + threadIdx.x; e < lim; e += 256) {
        int sv = src[e], d = dst[e];
        int b = (sv >> CSHIFT) * B + (d >> BSHIFT);
        int slot = atomicAdd(&hist[b], 1);
        rec[cbase[b] + slot] = (unsigned)sv | ((unsigned)(d & (BSN - 1)) << SRCBITS);
    }
}

// ------- per super-bucket: count/scan 128 local dst, emit rowp + csr --------
// rowp[c*(N+1)+n] = start of node n's chunk-c edges; rowp[c*(N+1)+N] = chunk end.
__global__ void csr_build(const unsigned* __restrict__ rec, const int* __restrict__ bbase,
                          int* __restrict__ rowp, int* __restrict__ csr,
                          int N, int B) {
    __shared__ int cnt[BSN], excl[BSN], cur[BSN];
    int bid = blockIdx.x, t = threadIdx.x;
    int c = bid / B, b = bid - c * B;
    if (t < BSN) cnt[t] = 0;
    __syncthreads();
    int start = bbase[bid], end = bbase[bid + 1];
    for (int i = start + t; i < end; i += 256)
        atomicAdd(&cnt[rec[i] >> SRCBITS], 1);
    __syncthreads();
    if (t < BSN) excl[t] = cnt[t];
    __syncthreads();
    for (int off = 1; off < BSN; off <<= 1) {
        int a = 0;
        if (t < BSN && t >= off) a = excl[t - off];
        __syncthreads();
        if (t < BSN) excl[t] += a;
        __syncthreads();
    }
    if (t < BSN) {
        int inc = excl[t];
        int ex = inc - cnt[t];
        excl[t] = ex;
        cur[t] = 0;
        int n = b * BSN + t;
        if (n < N) rowp[(size_t)c * (N + 1) + n] = start + ex;
    }
    if (b == B - 1 && t == 0) rowp[(size_t)c * (N + 1) + N] = end;
    __syncthreads();
    for (int i = start + t; i < end; i += 256) {
        unsigned r = rec[i];
        int dl = r >> SRCBITS;
        int slot = atomicAdd(&cur[dl], 1);
        csr[start + excl[dl] + slot] = (int)(r & ((1u << SRCBITS) - 1));
    }
}

// ---------------- dinv from per-chunk row pointers --------------------------
__global__ void degk(const int* __restrict__ rowp, float* __restrict__ dinv,
                     int N, int C) {
    int n = blockIdx.x * 256 + threadIdx.x;
    if (n >= N) return;
    int deg = 0;
    for (int c = 0; c < C; ++c) {
        const int* rp = rowp + (size_t)c * (N + 1);
        deg += rp[n + 1] - rp[n];
    }
    dinv[n] = rsqrtf((float)deg + 1.0f);
}

// -------------------------- h0' = bf16((x @ W1) * dinv[n]) ------------------
__global__ void gemm1(const float* __restrict__ x, const float* __restrict__ W1,
                      const float* __restrict__ dinv, unsigned short* __restrict__ h0,
                      int N) {
    __shared__ float Ws[FIN * HID];
    __shared__ float xs[16 * FIN];
    const float4* W4 = (const float4*)W1;
    float4* Ws4 = (float4*)Ws;
#pragma unroll
    for (int j = 0; j < 8; ++j) Ws4[threadIdx.x + 256 * j] = W4[threadIdx.x + 256 * j];
    __syncthreads();

    int f0 = threadIdx.x & 31, f1 = f0 + 32;
    int slot = threadIdx.x >> 5;
    int n0 = slot * 2, n1 = n0 + 1;
    int ntiles = N >> 4;
    for (int tile = blockIdx.x; tile < ntiles; tile += gridDim.x) {
        int base = tile << 4;
        const float4* xg = (const float4*)(x + (size_t)base * FIN);
        float4* xs4 = (float4*)xs;
        xs4[threadIdx.x]       = xg[threadIdx.x];
        xs4[threadIdx.x + 256] = xg[threadIdx.x + 256];
        __syncthreads();
        float a00 = 0.f, a01 = 0.f, a10 = 0.f, a11 = 0.f;
#pragma unroll 8
        for (int k = 0; k < FIN; ++k) {
            float w0 = Ws[k * HID + f0], w1 = Ws[k * HID + f1];
            float x0 = xs[n0 * FIN + k], x1 = xs[n1 * FIN + k];
            a00 += x0 * w0; a01 += x0 * w1;
            a10 += x1 * w0; a11 += x1 * w1;
        }
        float d0 = dinv[base + n0], d1 = dinv[base + n1];
        size_t r0 = (size_t)(base + n0) * HID, r1 = (size_t)(base + n1) * HID;
        h0[r0 + f0] = f2bf(a00 * d0); h0[r0 + f1] = f2bf(a01 * d0);
        h0[r1 + f0] = f2bf(a10 * d1); h0[r1 + f1] = f2bf(a11 * d1);
        __syncthreads();
    }
}

// ---------------- phased pull: LDS acc, chunked gathers, soft grid barrier --
// mode 0: outp = bf16(relu(di*(acc+self) + b1) * di)   (pull1 -> h')
// mode 1: outp = bf16(di*(acc+self))                   (pull2 -> abar)
__global__ __launch_bounds__(512, 4) void pull_phased(
    const unsigned short* __restrict__ hp, const int* __restrict__ rowp,
    const int* __restrict__ csr, const float* __restrict__ dinv,
    const float* __restrict__ b1, unsigned short* __restrict__ outp,
    int* __restrict__ bar, int N, int C, int mode) {
    __shared__ float acc[NPB * HID];       // 50 KB
    float4* a4 = (float4*)acc;
    for (int i = threadIdx.x; i < NPB * (HID / 4); i += 512)
        a4[i] = float4{0.f, 0.f, 0.f, 0.f};
    __syncthreads();

    const int wave = threadIdx.x >> 6, lane = threadIdx.x & 63;
    const int blkbase = blockIdx.x * NPB;
    const int wbase = blkbase + wave * KN;
    const int nlim = min(wbase + KN, N);
    float* wacc = acc + (size_t)(wave * KN) * HID + lane;

    for (int c = 0; c < C; ++c) {
        if (wbase < nlim) {
            const int* rp = rowp + (size_t)c * (N + 1);
            int j    = __builtin_amdgcn_readfirstlane(rp[wbase]);
            int jend = __builtin_amdgcn_readfirstlane(rp[nlim]);
            int n    = wbase;
            int nend = __builtin_amdgcn_readfirstlane(rp[wbase + 1]);
            float run = 0.f;
            auto step = [&](float vi, int i) {
                if (j + i >= nend) {
                    unsafeAtomicAdd(&wacc[(n - wbase) * HID], run);
                    run = 0.f;
                    do { ++n; nend = __builtin_amdgcn_readfirstlane(rp[n + 1]); }
                    while (j + i >= nend);
                }
                run += vi;
            };
            while (j + 8 <= jend) {
                int s0 = csr[j], s1 = csr[j + 1], s2 = csr[j + 2], s3 = csr[j + 3];
                int s4 = csr[j + 4], s5 = csr[j + 5], s6 = csr[j + 6], s7 = csr[j + 7];
                float v0 = bf2f(hp[(size_t)s0 * HID + lane]);
                float v1 = bf2f(hp[(size_t)s1 * HID + lane]);
                float v2 = bf2f(hp[(size_t)s2 * HID + lane]);
                float v3 = bf2f(hp[(size_t)s3 * HID + lane]);
                float v4 = bf2f(hp[(size_t)s4 * HID + lane]);
                float v5 = bf2f(hp[(size_t)s5 * HID + lane]);
                float v6 = bf2f(hp[(size_t)s6 * HID + lane]);
                float v7 = bf2f(hp[(size_t)s7 * HID + lane]);
                step(v0, 0); step(v1, 1); step(v2, 2); step(v3, 3);
                step(v4, 4); step(v5, 5); step(v6, 6); step(v7, 7);
                j += 8;
            }
            while (j < jend) {
                int s0 = csr[j];
                float v0 = bf2f(hp[(size_t)s0 * HID + lane]);
                step(v0, 0);
                j += 1;
            }
            unsafeAtomicAdd(&wacc[(n - wbase) * HID], run);
        }
        softbar(&bar[c], (int)gridDim.x);
    }

    float bl = b1[lane];
#pragma unroll
    for (int k = 0; k < KN; ++k) {
        int n = wbase + k;
        if (n >= nlim) break;
        float a = wacc[k * HID];
        a += bf2f(hp[(size_t)n * HID + lane]);
        float di = dinv[n];
        if (mode == 0) {
            float v = di * a + bl;
            v = v > 0.f ? v : 0.f;
            outp[(size_t)n * HID + lane] = f2bf(v * di);
        } else {
            outp[(size_t)n * HID + lane] = f2bf(di * a);
        }
    }
}

// ---------------- out = abar @ [Wmu|Wls] + [bmu|bls] via MFMA ---------------
__global__ __launch_bounds__(256, 4) void gemm2_mfma(
    const unsigned short* __restrict__ abar,
    const float* __restrict__ Wmu, const float* __restrict__ bmu,
    const float* __restrict__ Wls, const float* __restrict__ bls,
    float* __restrict__ out, int N) {
    int wave = threadIdx.x >> 6, lane = threadIdx.x & 63;
    int m = lane & 15, q = lane >> 4;
    // B fragments: B[k][col], k = kk*32 + q*8 + jj, col = ct*16 + m
    short8 bf[4][2];
#pragma unroll
    for (int ct = 0; ct < 4; ++ct)
#pragma unroll
        for (int kk = 0; kk < 2; ++kk) {
            short8 tf;
#pragma unroll
            for (int jj = 0; jj < 8; ++jj) {
                int k = kk * 32 + q * 8 + jj;
                int col = ct * 16 + m;
                float w = (col < 32) ? Wmu[k * 32 + col] : Wls[k * 32 + (col - 32)];
                tf[jj] = (short)f2bf(w);
            }
            bf[ct][kk] = tf;
        }
    float bias[4];
#pragma unroll
    for (int ct = 0; ct < 4; ++ct) {
        int col = ct * 16 + m;
        bias[ct] = (col < 32) ? bmu[col] : bls[col - 32];
    }
    int ntiles = N >> 4;                    // N % 16 == 0
    int gw = blockIdx.x * 4 + wave;
    int nw = gridDim.x * 4;
    for (int t = gw; t < ntiles; t += nw) {
        int nbase = t << 4;
        const unsigned short* arow = abar + (size_t)(nbase + m) * HID;
        short8 a0 = *((const short8*)(arow + q * 8));
        short8 a1 = *((const short8*)(arow + 32 + q * 8));
        floatx4 cacc[4];
#pragma unroll
        for (int ct = 0; ct < 4; ++ct) cacc[ct] = floatx4{0.f, 0.f, 0.f, 0.f};
#pragma unroll
        for (int ct = 0; ct < 4; ++ct) {
            cacc[ct] = __builtin_amdgcn_mfma_f32_16x16x32_bf16(a0, bf[ct][0], cacc[ct], 0, 0, 0);
            cacc[ct] = __builtin_amdgcn_mfma_f32_16x16x32_bf16(a1, bf[ct][1], cacc[ct], 0, 0, 0);
        }
        // C/D: col = lane&15 (output feature), row = q*4 + r (node)
#pragma unroll
        for (int ct = 0; ct < 4; ++ct) {
            int col = ct * 16 + m;
            int which = col >> 5, o = col & 31;
#pragma unroll
            for (int r = 0; r < 4; ++r) {
                int n = nbase + q * 4 + r;
                out[(size_t)which * N * 32 + (size_t)n * 32 + o] = cacc[ct][r] + bias[ct];
            }
        }
    }
}

// ---------------------------------------------------------------------------
extern "C" void kernel_launch(void* const* d_in, const int* in_sizes, int n_in,
                              void* d_out, int out_size, void* d_ws, size_t ws_size,
                              hipStream_t stream) {
    const float* x   = (const float*)d_in[0];
    const int*   ei  = (const int*)d_in[1];
    const float* W1  = (const float*)d_in[2];
    const float* b1  = (const float*)d_in[3];
    const float* Wmu = (const float*)d_in[4];
    const float* bmu = (const float*)d_in[5];
    const float* Wls = (const float*)d_in[6];
    const float* bls = (const float*)d_in[7];
    int N = in_sizes[0] / FIN;
    int E = in_sizes[1] / 2;
    const int* src = ei;
    const int* dst = ei + E;
    float* out = (float*)d_out;

    int B = (N + BSN - 1) / BSN;            // 782
    int C = (N + CHUNK - 1) / CHUNK;        // 7
    int SB = B * C;                         // 5474 (<= MAXSB)
    int nbin = (E + EPB - 1) / EPB;         // 196

    // ws layout (4-byte units):
    // dinv[N] | rowp[C*(N+1)] | bbase[SB+1] | bcur[SB] | bar[32] | csr[E] |
    // bufA[N*64 bf16] | region2[max(E*4, N*128) bytes] (rec, then bufB)
    float* dinv  = (float*)d_ws;
    int*   rowp  = (int*)(dinv + N);
    int*   bbase = rowp + (size_t)C * (N + 1);
    int*   bcur  = bbase + (SB + 1);
    int*   bar   = bcur + SB;
    int*   csr   = bar + 32;
    unsigned short* bufA = (unsigned short*)(csr + E);          // h0' / abar
    char* region2 = (char*)(bufA + (size_t)N * HID);
    unsigned* rec        = (unsigned*)region2;                  // dead after csr_build
    unsigned short* bufB = (unsigned short*)region2;            // h'

    // zero bucket cursors + barrier counters (contiguous)
    hipMemsetAsync(bcur, 0, (size_t)(SB + 32) * sizeof(int), stream);

    bin_count<<<nbin, 256, 0, stream>>>(src, dst, bcur, E, B);
    scan_bkt<<<1, 1024, 0, stream>>>(bcur, bbase, E, SB);
    bin_fill<<<nbin, 256, 0, stream>>>(src, dst, bcur, rec, E, B);
    csr_build<<<SB, 256, 0, stream>>>(rec, bbase, rowp, csr, N, B);
    degk<<<(N + 255) / 256, 256, 0, stream>>>(rowp, dinv, N, C);

    gemm1<<<1024, 256, 0, stream>>>(x, W1, dinv, bufA, N);

    int pgrid = (N + NPB - 1) / NPB;        // 500
    pull_phased<<<pgrid, 512, 0, stream>>>(bufA, rowp, csr, dinv, b1, bufB,
                                           bar, N, C, 0);
    pull_phased<<<pgrid, 512, 0, stream>>>(bufB, rowp, csr, dinv, b1, bufA,
                                           bar + 16, N, C, 1);

    gemm2_mfma<<<256, 256, 0, stream>>>(bufA, Wmu, bmu, Wls, bls, out, N);
}

// Round 7
// 386.865 us; speedup vs baseline: 3.3177x; 3.3177x over previous
//
#include <hip/hip_runtime.h>
#include <hip/hip_bf16.h>

#define FIN 128
#define HID 64
#define HHID 32            // half-feature block
#define BSN 128            // nodes per bucket
#define BSHIFT 7
#define SRCBITS 20         // src fits in 20 bits (N < 1M)
#define EPB 8192           // edges per binning block

typedef __attribute__((ext_vector_type(8))) short short8;
typedef __attribute__((ext_vector_type(4))) float floatx4;

__device__ __forceinline__ float bf2f(unsigned short u) {
    union { unsigned int i; float f; } c;
    c.i = ((unsigned int)u) << 16;
    return c.f;
}

__device__ __forceinline__ unsigned short f2bf(float f) {
    union { float f; unsigned int i; } c;
    c.f = f;
    unsigned int u = c.i;
    unsigned int r = (u + 0x7FFFu + ((u >> 16) & 1u)) >> 16;   // RNE
    return (unsigned short)r;
}

// ---------------- bucket histogram (counts into bcur) ----------------------
__global__ void bin_count(const int* __restrict__ dst, int* __restrict__ bcnt,
                          int E, int B) {
    __shared__ int hist[1024];
    for (int i = threadIdx.x; i < 1024; i += 256) hist[i] = 0;
    __syncthreads();
    int base = blockIdx.x * EPB;
    int lim = min(base + EPB, E);
    for (int e = base + threadIdx.x; e < lim; e += 256)
        atomicAdd(&hist[dst[e] >> BSHIFT], 1);
    __syncthreads();
    for (int b = threadIdx.x; b < B; b += 256)
        if (hist[b]) atomicAdd(&bcnt[b], hist[b]);
}

// ---------------- scan bucket counts; bcnt becomes chunk cursor ------------
__global__ void scan_bkt(int* __restrict__ bcnt, int* __restrict__ bbase,
                         int E, int B) {
    __shared__ int s[1024];
    int t = threadIdx.x;
    int v = (t < B) ? bcnt[t] : 0;
    s[t] = v;
    __syncthreads();
    for (int off = 1; off < 1024; off <<= 1) {
        int a = (t >= off) ? s[t - off] : 0;
        __syncthreads();
        s[t] += a;
        __syncthreads();
    }
    if (t < B) { int ex = s[t] - v; bbase[t] = ex; bcnt[t] = ex; }
    if (t == 0) bbase[B] = E;
}

// ---------------- scatter packed records into per-bucket chunks ------------
__global__ void bin_fill(const int* __restrict__ src, const int* __restrict__ dst,
                         int* __restrict__ bcur, unsigned* __restrict__ rec, int E) {
    __shared__ int hist[1024];
    __shared__ int cbase[1024];
    for (int i = threadIdx.x; i < 1024; i += 256) hist[i] = 0;
    __syncthreads();
    int base = blockIdx.x * EPB;
    int lim = min(base + EPB, E);
    for (int e = base + threadIdx.x; e < lim; e += 256)
        atomicAdd(&hist[dst[e] >> BSHIFT], 1);
    __syncthreads();
    for (int b = threadIdx.x; b < 1024; b += 256) {
        int c = hist[b];
        cbase[b] = c ? atomicAdd(&bcur[b], c) : 0;   // one claim per (block,bucket)
    }
    __syncthreads();
    for (int i = threadIdx.x; i < 1024; i += 256) hist[i] = 0;
    __syncthreads();
    for (int e = base + threadIdx.x; e < lim; e += 256) {
        int d = dst[e];
        int b = d >> BSHIFT;
        int slot = atomicAdd(&hist[b], 1);           // LDS cursor (fast)
        rec[cbase[b] + slot] = (unsigned)src[e] | ((unsigned)(d & (BSN - 1)) << SRCBITS);
    }
}

// ------- per-bucket: count/scan 128 local nodes, emit row/rend/dinv/csr ----
__global__ void csr_build(const unsigned* __restrict__ rec, const int* __restrict__ bbase,
                          int* __restrict__ row, int* __restrict__ rend,
                          int* __restrict__ csr, float* __restrict__ dinv, int N) {
    __shared__ int cnt[BSN], excl[BSN], cur[BSN];
    int b = blockIdx.x, t = threadIdx.x;
    if (t < BSN) cnt[t] = 0;
    __syncthreads();
    int start = bbase[b], end = bbase[b + 1];
    for (int i = start + t; i < end; i += 256)
        atomicAdd(&cnt[rec[i] >> SRCBITS], 1);
    __syncthreads();
    if (t < BSN) excl[t] = cnt[t];
    __syncthreads();
    for (int off = 1; off < BSN; off <<= 1) {        // Hillis-Steele inclusive
        int a = 0;
        if (t < BSN && t >= off) a = excl[t - off];
        __syncthreads();
        if (t < BSN) excl[t] += a;
        __syncthreads();
    }
    if (t < BSN) {
        int inc = excl[t];
        int ex = inc - cnt[t];
        excl[t] = ex;                                // now exclusive
        cur[t] = 0;
        int n = b * BSN + t;
        if (n < N) {
            row[n]  = start + ex;
            rend[n] = start + inc;
            dinv[n] = rsqrtf((float)cnt[t] + 1.0f);
        }
    }
    __syncthreads();
    for (int i = start + t; i < end; i += 256) {     // hot 8KB region permute
        unsigned r = rec[i];
        int dl = r >> SRCBITS;
        int slot = atomicAdd(&cur[dl], 1);
        csr[start + excl[dl] + slot] = (int)(r & ((1u << SRCBITS) - 1));
    }
}

// ------- h0 blocked: lo[n*32+f] = bf16((x@W1)[n][f]*dinv), hi = features 32..63
__global__ void gemm1(const float* __restrict__ x, const float* __restrict__ W1,
                      const float* __restrict__ dinv,
                      unsigned short* __restrict__ lo, unsigned short* __restrict__ hi,
                      int N) {
    __shared__ float Ws[FIN * HID];
    __shared__ float xs[16 * FIN];
    const float4* W4 = (const float4*)W1;
    float4* Ws4 = (float4*)Ws;
#pragma unroll
    for (int j = 0; j < 8; ++j) Ws4[threadIdx.x + 256 * j] = W4[threadIdx.x + 256 * j];
    __syncthreads();

    int f0 = threadIdx.x & 31, f1 = f0 + 32;
    int slot = threadIdx.x >> 5;
    int n0 = slot * 2, n1 = n0 + 1;
    int ntiles = N >> 4;
    for (int tile = blockIdx.x; tile < ntiles; tile += gridDim.x) {
        int base = tile << 4;
        const float4* xg = (const float4*)(x + (size_t)base * FIN);
        float4* xs4 = (float4*)xs;
        xs4[threadIdx.x]       = xg[threadIdx.x];
        xs4[threadIdx.x + 256] = xg[threadIdx.x + 256];
        __syncthreads();
        float a00 = 0.f, a01 = 0.f, a10 = 0.f, a11 = 0.f;
#pragma unroll 8
        for (int k = 0; k < FIN; ++k) {
            float w0 = Ws[k * HID + f0], w1 = Ws[k * HID + f1];
            float x0 = xs[n0 * FIN + k], x1 = xs[n1 * FIN + k];
            a00 += x0 * w0; a01 += x0 * w1;
            a10 += x1 * w0; a11 += x1 * w1;
        }
        float d0 = dinv[base + n0], d1 = dinv[base + n1];
        size_t r0 = (size_t)(base + n0) * HHID, r1 = (size_t)(base + n1) * HHID;
        lo[r0 + f0] = f2bf(a00 * d0); hi[r0 + f0] = f2bf(a01 * d0);
        lo[r1 + f0] = f2bf(a10 * d1); hi[r1 + f0] = f2bf(a11 * d1);
        __syncthreads();
    }
}

// ---- half-feature pull: wave per dst node; lanes 0-31 even edges, 32-63 odd.
// 6.4MB gather footprint -> ~62% per-XCD L2 hit. Scalar (wave-uniform) indices.
// mode 0: out = bf16(relu(di*(acc+self) + b[f]) * di)
// mode 1: out = bf16(di*(acc+self))
__global__ void pull_half(const unsigned short* __restrict__ hp,
                          const int* __restrict__ row, const int* __restrict__ rend,
                          const int* __restrict__ csr, const float* __restrict__ dinv,
                          const float* __restrict__ b1,
                          unsigned short* __restrict__ outp, int N, int mode) {
    int wave = threadIdx.x >> 6, lane = threadIdx.x & 63;
    int n = blockIdx.x * 4 + wave;
    if (n >= N) return;
    int half = lane >> 5, f = lane & 31;
    int start = __builtin_amdgcn_readfirstlane(row[n]);
    int end   = __builtin_amdgcn_readfirstlane(rend[n]);
    float a0 = 0.f, a1 = 0.f, a2 = 0.f, a3 = 0.f;
    int j = start;
    for (; j + 8 <= end; j += 8) {
        int e0 = csr[j],     e1 = csr[j + 1], e2 = csr[j + 2], e3 = csr[j + 3];
        int e4 = csr[j + 4], e5 = csr[j + 5], e6 = csr[j + 6], e7 = csr[j + 7];
        int i0 = half ? e1 : e0, i1 = half ? e3 : e2;
        int i2 = half ? e5 : e4, i3 = half ? e7 : e6;
        a0 += bf2f(hp[(size_t)i0 * HHID + f]);
        a1 += bf2f(hp[(size_t)i1 * HHID + f]);
        a2 += bf2f(hp[(size_t)i2 * HHID + f]);
        a3 += bf2f(hp[(size_t)i3 * HHID + f]);
    }
    for (; j + 2 <= end; j += 2) {
        int e0 = csr[j], e1 = csr[j + 1];
        int i0 = half ? e1 : e0;
        a0 += bf2f(hp[(size_t)i0 * HHID + f]);
    }
    if (j < end) {
        int e0 = csr[j];
        float v = bf2f(hp[(size_t)e0 * HHID + f]);
        a0 += half ? 0.f : v;
    }
    float acc = (a0 + a1) + (a2 + a3);
    acc += __shfl_xor(acc, 32);                 // combine even/odd halves
    acc += bf2f(hp[(size_t)n * HHID + f]);      // self-loop (same value both halves)
    float di = dinv[n];
    if (half == 0) {
        float v;
        if (mode == 0) {
            v = di * acc + b1[f];
            v = v > 0.f ? v : 0.f;
            v *= di;
        } else {
            v = di * acc;
        }
        outp[(size_t)n * HHID + f] = f2bf(v);
    }
}

// ---------------- out = abar @ [Wmu|Wls] + [bmu|bls] via MFMA ---------------
// abar stored as blocked halves lo (features 0-31) / hi (32-63).
__global__ __launch_bounds__(256, 4) void gemm2_mfma(
    const unsigned short* __restrict__ lo, const unsigned short* __restrict__ hi,
    const float* __restrict__ Wmu, const float* __restrict__ bmu,
    const float* __restrict__ Wls, const float* __restrict__ bls,
    float* __restrict__ out, int N) {
    int wave = threadIdx.x >> 6, lane = threadIdx.x & 63;
    int m = lane & 15, q = lane >> 4;
    // B fragments: B[k][col], k = kk*32 + q*8 + jj, col = ct*16 + m
    short8 bf[4][2];
#pragma unroll
    for (int ct = 0; ct < 4; ++ct)
#pragma unroll
        for (int kk = 0; kk < 2; ++kk) {
            short8 tf;
#pragma unroll
            for (int jj = 0; jj < 8; ++jj) {
                int k = kk * 32 + q * 8 + jj;
                int col = ct * 16 + m;
                float w = (col < 32) ? Wmu[k * 32 + col] : Wls[k * 32 + (col - 32)];
                tf[jj] = (short)f2bf(w);
            }
            bf[ct][kk] = tf;
        }
    float bias[4];
#pragma unroll
    for (int ct = 0; ct < 4; ++ct) {
        int col = ct * 16 + m;
        bias[ct] = (col < 32) ? bmu[col] : bls[col - 32];
    }
    int ntiles = N >> 4;                    // N % 16 == 0
    int gw = blockIdx.x * 4 + wave;
    int nw = gridDim.x * 4;
    for (int t = gw; t < ntiles; t += nw) {
        int nbase = t << 4;
        // A fragment: A[m][k], k = kk*32 + q*8 + jj -> kk=0 from lo, kk=1 from hi
        short8 a0 = *((const short8*)(lo + (size_t)(nbase + m) * HHID + q * 8));
        short8 a1 = *((const short8*)(hi + (size_t)(nbase + m) * HHID + q * 8));
        floatx4 cacc[4];
#pragma unroll
        for (int ct = 0; ct < 4; ++ct) cacc[ct] = floatx4{0.f, 0.f, 0.f, 0.f};
#pragma unroll
        for (int ct = 0; ct < 4; ++ct) {
            cacc[ct] = __builtin_amdgcn_mfma_f32_16x16x32_bf16(a0, bf[ct][0], cacc[ct], 0, 0, 0);
            cacc[ct] = __builtin_amdgcn_mfma_f32_16x16x32_bf16(a1, bf[ct][1], cacc[ct], 0, 0, 0);
        }
        // C/D: col = lane&15 (output feature), row = q*4 + r (node)
#pragma unroll
        for (int ct = 0; ct < 4; ++ct) {
            int col = ct * 16 + m;
            int which = col >> 5, o = col & 31;
#pragma unroll
            for (int r = 0; r < 4; ++r) {
                int n = nbase + q * 4 + r;
                out[(size_t)which * N * 32 + (size_t)n * 32 + o] = cacc[ct][r] + bias[ct];
            }
        }
    }
}

// ---------------------------------------------------------------------------
extern "C" void kernel_launch(void* const* d_in, const int* in_sizes, int n_in,
                              void* d_out, int out_size, void* d_ws, size_t ws_size,
                              hipStream_t stream) {
    const float* x   = (const float*)d_in[0];
    const int*   ei  = (const int*)d_in[1];
    const float* W1  = (const float*)d_in[2];
    const float* b1  = (const float*)d_in[3];
    const float* Wmu = (const float*)d_in[4];
    const float* bmu = (const float*)d_in[5];
    const float* Wls = (const float*)d_in[6];
    const float* bls = (const float*)d_in[7];
    int N = in_sizes[0] / FIN;
    int E = in_sizes[1] / 2;
    const int* src = ei;
    const int* dst = ei + E;
    float* out = (float*)d_out;

    int B = (N + BSN - 1) / BSN;            // 782 buckets
    int nbin = (E + EPB - 1) / EPB;         // 196 binning blocks

    // ws layout (4-byte units):
    // dinv[N] | row[N] | rend[N] | bbase[B+1] | bcur[B] | csr[E] |
    // bufA[N*64 bf16] | region2[max(E*4, N*128) bytes] (rec during build, then bufB)
    float* dinv  = (float*)d_ws;
    int*   row   = (int*)(dinv + N);
    int*   rend  = row + N;
    int*   bbase = rend + N;
    int*   bcur  = bbase + (B + 1);
    int*   csr   = bcur + B;
    unsigned short* bufA = (unsigned short*)(csr + E);          // h0' / abar (blocked)
    char* region2 = (char*)(bufA + (size_t)N * HID);
    unsigned* rec        = (unsigned*)region2;                  // dead after csr_build
    unsigned short* bufB = (unsigned short*)region2;            // h' (blocked)

    unsigned short* A_lo = bufA;
    unsigned short* A_hi = bufA + (size_t)N * HHID;
    unsigned short* B_lo = bufB;
    unsigned short* B_hi = bufB + (size_t)N * HHID;

    hipMemsetAsync(bcur, 0, (size_t)B * sizeof(int), stream);
    bin_count<<<nbin, 256, 0, stream>>>(dst, bcur, E, B);
    scan_bkt<<<1, 1024, 0, stream>>>(bcur, bbase, E, B);
    bin_fill<<<nbin, 256, 0, stream>>>(src, dst, bcur, rec, E);
    csr_build<<<B, 256, 0, stream>>>(rec, bbase, row, rend, csr, dinv, N);

    gemm1<<<1024, 256, 0, stream>>>(x, W1, dinv, A_lo, A_hi, N);

    int pgrid = (N + 3) / 4;
    // layer 1: two half-feature passes (sequential -> 6.4MB hot set each)
    pull_half<<<pgrid, 256, 0, stream>>>(A_lo, row, rend, csr, dinv, b1,      B_lo, N, 0);
    pull_half<<<pgrid, 256, 0, stream>>>(A_hi, row, rend, csr, dinv, b1 + 32, B_hi, N, 0);
    // layer 2 shared aggregation: abar halves
    pull_half<<<pgrid, 256, 0, stream>>>(B_lo, row, rend, csr, dinv, b1,      A_lo, N, 1);
    pull_half<<<pgrid, 256, 0, stream>>>(B_hi, row, rend, csr, dinv, b1,      A_hi, N, 1);

    gemm2_mfma<<<256, 256, 0, stream>>>(A_lo, A_hi, Wmu, bmu, Wls, bls, out, N);
}

// Round 8
// 308.705 us; speedup vs baseline: 4.1577x; 1.2532x over previous
//
#include <hip/hip_runtime.h>
#include <hip/hip_bf16.h>

#define FIN 128
#define HID 64
#define BSN 128            // nodes per bucket
#define BSHIFT 7
#define SRCBITS 20         // src fits in 20 bits (N < 1M)
#define EPB 8192           // edges per binning block

typedef __attribute__((ext_vector_type(8))) short short8;
typedef __attribute__((ext_vector_type(4))) float floatx4;

__device__ __forceinline__ float bf2f(unsigned short u) {
    union { unsigned int i; float f; } c;
    c.i = ((unsigned int)u) << 16;
    return c.f;
}

__device__ __forceinline__ unsigned short f2bf(float f) {
    union { float f; unsigned int i; } c;
    c.f = f;
    unsigned int u = c.i;
    unsigned int r = (u + 0x7FFFu + ((u >> 16) & 1u)) >> 16;   // RNE
    return (unsigned short)r;
}

// ---------------- bucket histogram (counts into bcur) ----------------------
__global__ void bin_count(const int* __restrict__ dst, int* __restrict__ bcnt,
                          int E, int B) {
    __shared__ int hist[1024];
    for (int i = threadIdx.x; i < 1024; i += 256) hist[i] = 0;
    __syncthreads();
    int base = blockIdx.x * EPB;
    int lim = min(base + EPB, E);
    for (int e = base + threadIdx.x; e < lim; e += 256)
        atomicAdd(&hist[dst[e] >> BSHIFT], 1);
    __syncthreads();
    for (int b = threadIdx.x; b < B; b += 256)
        if (hist[b]) atomicAdd(&bcnt[b], hist[b]);
}

// ---------------- scan bucket counts; bcnt becomes chunk cursor ------------
__global__ void scan_bkt(int* __restrict__ bcnt, int* __restrict__ bbase,
                         int E, int B) {
    __shared__ int s[1024];
    int t = threadIdx.x;
    int v = (t < B) ? bcnt[t] : 0;
    s[t] = v;
    __syncthreads();
    for (int off = 1; off < 1024; off <<= 1) {
        int a = (t >= off) ? s[t - off] : 0;
        __syncthreads();
        s[t] += a;
        __syncthreads();
    }
    if (t < B) { int ex = s[t] - v; bbase[t] = ex; bcnt[t] = ex; }
    if (t == 0) bbase[B] = E;
}

// ---------------- scatter packed records into per-bucket chunks ------------
__global__ void bin_fill(const int* __restrict__ src, const int* __restrict__ dst,
                         int* __restrict__ bcur, unsigned* __restrict__ rec, int E) {
    __shared__ int hist[1024];
    __shared__ int cbase[1024];
    for (int i = threadIdx.x; i < 1024; i += 256) hist[i] = 0;
    __syncthreads();
    int base = blockIdx.x * EPB;
    int lim = min(base + EPB, E);
    for (int e = base + threadIdx.x; e < lim; e += 256)
        atomicAdd(&hist[dst[e] >> BSHIFT], 1);
    __syncthreads();
    for (int b = threadIdx.x; b < 1024; b += 256) {
        int c = hist[b];
        cbase[b] = c ? atomicAdd(&bcur[b], c) : 0;   // one claim per (block,bucket)
    }
    __syncthreads();
    for (int i = threadIdx.x; i < 1024; i += 256) hist[i] = 0;
    __syncthreads();
    for (int e = base + threadIdx.x; e < lim; e += 256) {
        int d = dst[e];
        int b = d >> BSHIFT;
        int slot = atomicAdd(&hist[b], 1);           // LDS cursor (fast)
        rec[cbase[b] + slot] = (unsigned)src[e] | ((unsigned)(d & (BSN - 1)) << SRCBITS);
    }
}

// ------- per-bucket: count/scan 128 local nodes, emit row/rend/dinv/csr ----
__global__ void csr_build(const unsigned* __restrict__ rec, const int* __restrict__ bbase,
                          int* __restrict__ row, int* __restrict__ rend,
                          int* __restrict__ csr, float* __restrict__ dinv, int N) {
    __shared__ int cnt[BSN], excl[BSN], cur[BSN];
    int b = blockIdx.x, t = threadIdx.x;
    if (t < BSN) cnt[t] = 0;
    __syncthreads();
    int start = bbase[b], end = bbase[b + 1];
    for (int i = start + t; i < end; i += 256)
        atomicAdd(&cnt[rec[i] >> SRCBITS], 1);
    __syncthreads();
    if (t < BSN) excl[t] = cnt[t];
    __syncthreads();
    for (int off = 1; off < BSN; off <<= 1) {        // Hillis-Steele inclusive
        int a = 0;
        if (t < BSN && t >= off) a = excl[t - off];
        __syncthreads();
        if (t < BSN) excl[t] += a;
        __syncthreads();
    }
    if (t < BSN) {
        int inc = excl[t];
        int ex = inc - cnt[t];
        excl[t] = ex;                                // now exclusive
        cur[t] = 0;
        int n = b * BSN + t;
        if (n < N) {
            row[n]  = start + ex;
            rend[n] = start + inc;
            dinv[n] = rsqrtf((float)cnt[t] + 1.0f);
        }
    }
    __syncthreads();
    for (int i = start + t; i < end; i += 256) {     // hot 8KB region permute
        unsigned r = rec[i];
        int dl = r >> SRCBITS;
        int slot = atomicAdd(&cur[dl], 1);
        csr[start + excl[dl] + slot] = (int)(r & ((1u << SRCBITS) - 1));
    }
}

// --------- h0' = bf16((x @ W1) * dinv[n]) via MFMA, fp32->bf16 in-register --
// wave per 16-node tile; W1 (128x64) held as 16 B-frags in registers.
__global__ __launch_bounds__(256) void gemm1_mfma(
    const float* __restrict__ x, const float* __restrict__ W1,
    const float* __restrict__ dinv, unsigned short* __restrict__ h0, int N) {
    int wave = threadIdx.x >> 6, lane = threadIdx.x & 63;
    int m = lane & 15, q = lane >> 4;
    // B frags: B[k][col], col = ct*16+m, k = kk*32 + q*8 + jj
    short8 bfr[4][4];
#pragma unroll
    for (int ct = 0; ct < 4; ++ct)
#pragma unroll
        for (int kk = 0; kk < 4; ++kk) {
            short8 tf;
#pragma unroll
            for (int jj = 0; jj < 8; ++jj)
                tf[jj] = (short)f2bf(W1[(kk * 32 + q * 8 + jj) * HID + ct * 16 + m]);
            bfr[ct][kk] = tf;
        }
    int ntiles = N >> 4;                    // N % 16 == 0
    for (int t = blockIdx.x * 4 + wave; t < ntiles; t += gridDim.x * 4) {
        int nbase = t << 4;
        const float* xr = x + (size_t)(nbase + m) * FIN + q * 8;
        short8 afr[4];
#pragma unroll
        for (int kk = 0; kk < 4; ++kk) {
            float4 p0 = *((const float4*)(xr + kk * 32));
            float4 p1 = *((const float4*)(xr + kk * 32 + 4));
            short8 ta;
            ta[0] = (short)f2bf(p0.x); ta[1] = (short)f2bf(p0.y);
            ta[2] = (short)f2bf(p0.z); ta[3] = (short)f2bf(p0.w);
            ta[4] = (short)f2bf(p1.x); ta[5] = (short)f2bf(p1.y);
            ta[6] = (short)f2bf(p1.z); ta[7] = (short)f2bf(p1.w);
            afr[kk] = ta;
        }
        floatx4 cacc[4];
#pragma unroll
        for (int ct = 0; ct < 4; ++ct) cacc[ct] = floatx4{0.f, 0.f, 0.f, 0.f};
#pragma unroll
        for (int ct = 0; ct < 4; ++ct)
#pragma unroll
            for (int kk = 0; kk < 4; ++kk)
                cacc[ct] = __builtin_amdgcn_mfma_f32_16x16x32_bf16(afr[kk], bfr[ct][kk], cacc[ct], 0, 0, 0);
        float4 dv = *((const float4*)(dinv + nbase + q * 4));
        // C/D: within-tile col = m (output feature tile ct), node = q*4 + r
#pragma unroll
        for (int ct = 0; ct < 4; ++ct) {
#pragma unroll
            for (int r = 0; r < 4; ++r) {
                float d = (r == 0) ? dv.x : (r == 1) ? dv.y : (r == 2) ? dv.z : dv.w;
                int n = nbase + q * 4 + r;
                h0[(size_t)n * HID + ct * 16 + m] = f2bf(cacc[ct][r] * d);
            }
        }
    }
}

// ---- pull: wave per dst node, lane = feature (128 B row gathers), 8 accs.
// mode 0: outp = bf16(relu(di*(acc+self) + b1[f]) * di)   (-> h')
// mode 1: outp = bf16(di*(acc+self))                      (-> abar)
__global__ void pull(const unsigned short* __restrict__ hp,
                     const int* __restrict__ row, const int* __restrict__ rend,
                     const int* __restrict__ csr, const float* __restrict__ dinv,
                     const float* __restrict__ b1,
                     unsigned short* __restrict__ outp, int N, int mode) {
    int wave = threadIdx.x >> 6, lane = threadIdx.x & 63;
    int n = blockIdx.x * 4 + wave;
    if (n >= N) return;
    int start = __builtin_amdgcn_readfirstlane(row[n]);
    int end   = __builtin_amdgcn_readfirstlane(rend[n]);
    float a0 = 0.f, a1 = 0.f, a2 = 0.f, a3 = 0.f;
    float a4 = 0.f, a5 = 0.f, a6 = 0.f, a7 = 0.f;
    int j = start;
    for (; j + 8 <= end; j += 8) {
        int s0 = csr[j],     s1 = csr[j + 1], s2 = csr[j + 2], s3 = csr[j + 3];
        int s4 = csr[j + 4], s5 = csr[j + 5], s6 = csr[j + 6], s7 = csr[j + 7];
        a0 += bf2f(hp[(size_t)s0 * HID + lane]);
        a1 += bf2f(hp[(size_t)s1 * HID + lane]);
        a2 += bf2f(hp[(size_t)s2 * HID + lane]);
        a3 += bf2f(hp[(size_t)s3 * HID + lane]);
        a4 += bf2f(hp[(size_t)s4 * HID + lane]);
        a5 += bf2f(hp[(size_t)s5 * HID + lane]);
        a6 += bf2f(hp[(size_t)s6 * HID + lane]);
        a7 += bf2f(hp[(size_t)s7 * HID + lane]);
    }
    for (; j < end; ++j) {
        int s = csr[j];
        a0 += bf2f(hp[(size_t)s * HID + lane]);
    }
    float acc = ((a0 + a1) + (a2 + a3)) + ((a4 + a5) + (a6 + a7));
    acc += bf2f(hp[(size_t)n * HID + lane]);        // self-loop
    float di = dinv[n];
    float v;
    if (mode == 0) {
        v = di * acc + b1[lane];
        v = v > 0.f ? v : 0.f;
        v *= di;
    } else {
        v = di * acc;
    }
    outp[(size_t)n * HID + lane] = f2bf(v);
}

// ---------------- out = abar @ [Wmu|Wls] + [bmu|bls] via MFMA ---------------
// abar interleaved [N][64] bf16.
__global__ __launch_bounds__(256, 4) void gemm2_mfma(
    const unsigned short* __restrict__ abar,
    const float* __restrict__ Wmu, const float* __restrict__ bmu,
    const float* __restrict__ Wls, const float* __restrict__ bls,
    float* __restrict__ out, int N) {
    int wave = threadIdx.x >> 6, lane = threadIdx.x & 63;
    int m = lane & 15, q = lane >> 4;
    short8 bfr[4][2];
#pragma unroll
    for (int ct = 0; ct < 4; ++ct)
#pragma unroll
        for (int kk = 0; kk < 2; ++kk) {
            short8 tf;
#pragma unroll
            for (int jj = 0; jj < 8; ++jj) {
                int k = kk * 32 + q * 8 + jj;
                int col = ct * 16 + m;
                float w = (col < 32) ? Wmu[k * 32 + col] : Wls[k * 32 + (col - 32)];
                tf[jj] = (short)f2bf(w);
            }
            bfr[ct][kk] = tf;
        }
    float bias[4];
#pragma unroll
    for (int ct = 0; ct < 4; ++ct) {
        int col = ct * 16 + m;
        bias[ct] = (col < 32) ? bmu[col] : bls[col - 32];
    }
    int ntiles = N >> 4;
    int gw = blockIdx.x * 4 + wave;
    int nw = gridDim.x * 4;
    for (int t = gw; t < ntiles; t += nw) {
        int nbase = t << 4;
        const unsigned short* arow = abar + (size_t)(nbase + m) * HID;
        short8 a0 = *((const short8*)(arow + q * 8));
        short8 a1 = *((const short8*)(arow + 32 + q * 8));
        floatx4 cacc[4];
#pragma unroll
        for (int ct = 0; ct < 4; ++ct) cacc[ct] = floatx4{0.f, 0.f, 0.f, 0.f};
#pragma unroll
        for (int ct = 0; ct < 4; ++ct) {
            cacc[ct] = __builtin_amdgcn_mfma_f32_16x16x32_bf16(a0, bfr[ct][0], cacc[ct], 0, 0, 0);
            cacc[ct] = __builtin_amdgcn_mfma_f32_16x16x32_bf16(a1, bfr[ct][1], cacc[ct], 0, 0, 0);
        }
#pragma unroll
        for (int ct = 0; ct < 4; ++ct) {
            int col = ct * 16 + m;
            int which = col >> 5, o = col & 31;
#pragma unroll
            for (int r = 0; r < 4; ++r) {
                int n = nbase + q * 4 + r;
                out[(size_t)which * N * 32 + (size_t)n * 32 + o] = cacc[ct][r] + bias[ct];
            }
        }
    }
}

// ---------------------------------------------------------------------------
extern "C" void kernel_launch(void* const* d_in, const int* in_sizes, int n_in,
                              void* d_out, int out_size, void* d_ws, size_t ws_size,
                              hipStream_t stream) {
    const float* x   = (const float*)d_in[0];
    const int*   ei  = (const int*)d_in[1];
    const float* W1  = (const float*)d_in[2];
    const float* b1  = (const float*)d_in[3];
    const float* Wmu = (const float*)d_in[4];
    const float* bmu = (const float*)d_in[5];
    const float* Wls = (const float*)d_in[6];
    const float* bls = (const float*)d_in[7];
    int N = in_sizes[0] / FIN;
    int E = in_sizes[1] / 2;
    const int* src = ei;
    const int* dst = ei + E;
    float* out = (float*)d_out;

    int B = (N + BSN - 1) / BSN;            // 782 buckets
    int nbin = (E + EPB - 1) / EPB;         // 196 binning blocks

    // ws layout (4-byte units):
    // dinv[N] | row[N] | rend[N] | bbase[B+1] | bcur[B] | csr[E] |
    // bufA[N*64 bf16] | region2[max(E*4, N*128) bytes] (rec during build, then bufB)
    float* dinv  = (float*)d_ws;
    int*   row   = (int*)(dinv + N);
    int*   rend  = row + N;
    int*   bbase = rend + N;
    int*   bcur  = bbase + (B + 1);
    int*   csr   = bcur + B;
    unsigned short* bufA = (unsigned short*)(csr + E);          // h0' / abar
    char* region2 = (char*)(bufA + (size_t)N * HID);
    unsigned* rec        = (unsigned*)region2;                  // dead after csr_build
    unsigned short* bufB = (unsigned short*)region2;            // h'

    hipMemsetAsync(bcur, 0, (size_t)B * sizeof(int), stream);
    bin_count<<<nbin, 256, 0, stream>>>(dst, bcur, E, B);
    scan_bkt<<<1, 1024, 0, stream>>>(bcur, bbase, E, B);
    bin_fill<<<nbin, 256, 0, stream>>>(src, dst, bcur, rec, E);
    csr_build<<<B, 256, 0, stream>>>(rec, bbase, row, rend, csr, dinv, N);

    gemm1_mfma<<<256, 256, 0, stream>>>(x, W1, dinv, bufA, N);

    int pgrid = (N + 3) / 4;
    pull<<<pgrid, 256, 0, stream>>>(bufA, row, rend, csr, dinv, b1, bufB, N, 0);
    pull<<<pgrid, 256, 0, stream>>>(bufB, row, rend, csr, dinv, b1, bufA, N, 1);

    gemm2_mfma<<<256, 256, 0, stream>>>(bufA, Wmu, bmu, Wls, bls, out, N);
}